// Round 3
// baseline (256.462 us; speedup 1.0000x reference)
//
#include <hip/hip_runtime.h>
#include <cstdint>

// CausalSelfAttention B=2 L=2048 D=1024 H=16 dh=64, fp32 in/out.
// Round 3:
//   prep : x -> bf16 ; [W_kq|W_v] -> wcat bf16 (3072 x 1024) ; W_o -> wot
//   g1   : fused kqv GEMM 4096x3072x1024 -> kqb (q pre-scaled 0.125) + vtb^T
//   attn : flash MFMA computing S^T (per-lane softmax state), Ktile=128
//   g2   : out = att @ Wo^T + b_o, split-K=2, fp32 atomicAdd into zeroed out
// GEMM: 128x128 tile, BK=64, global_load_lds width 16, XOR chunk swizzle.

#define LSEQ 2048
#define DM   1024
#define BL   4096   // B * LSEQ

using frag_ab = __attribute__((ext_vector_type(8))) short;  // 8 bf16
using f32x4   = __attribute__((ext_vector_type(4))) float;

__device__ __forceinline__ unsigned short f2bf(float f) {
  unsigned int u = __float_as_uint(f);
  u += 0x7fffu + ((u >> 16) & 1u);   // RNE (finite inputs only)
  return (unsigned short)(u >> 16);
}

__device__ __forceinline__ void load_lds16(const void* g, void* l) {
  __builtin_amdgcn_global_load_lds(
      (const __attribute__((address_space(1))) unsigned int*)g,
      (__attribute__((address_space(3))) unsigned int*)l, 16, 0, 0);
}

// ---------------- prep kernels ----------------

__global__ __launch_bounds__(256) void cast_bf16_kernel(
    const float* __restrict__ in, unsigned short* __restrict__ out, int n4)
{
  int i = (blockIdx.x * 256 + threadIdx.x);
  if (i < n4) {
    const float4 v = *(const float4*)&in[i * 4];
    ushort4 o;
    o.x = f2bf(v.x); o.y = f2bf(v.y); o.z = f2bf(v.z); o.w = f2bf(v.w);
    *(ushort4*)&out[i * 4] = o;
  }
}

// W (K x N fp32) -> Wt (N x K bf16)
__global__ __launch_bounds__(256) void transpose_cast_kernel(
    const float* __restrict__ W, unsigned short* __restrict__ Wt, int K, int N)
{
  __shared__ float tile[32][33];
  const int r  = threadIdx.x >> 3;        // 0..31
  const int c4 = (threadIdx.x & 7) * 4;   // 0..28
  const int kb = blockIdx.y * 32;
  const int nb = blockIdx.x * 32;

  const float4 v = *(const float4*)&W[(size_t)(kb + r) * N + nb + c4];
  tile[r][c4 + 0] = v.x; tile[r][c4 + 1] = v.y;
  tile[r][c4 + 2] = v.z; tile[r][c4 + 3] = v.w;
  __syncthreads();
  ushort4 o;
  o.x = f2bf(tile[c4 + 0][r]);
  o.y = f2bf(tile[c4 + 1][r]);
  o.z = f2bf(tile[c4 + 2][r]);
  o.w = f2bf(tile[c4 + 3][r]);
  *(ushort4*)&Wt[(size_t)(nb + r) * K + kb + c4] = o;
}

// ---------------- fused kqv GEMM ----------------
// A = xb [4096x1024], Bt = wcat [3072x1024] (rows 0..2047 = W_kq^T, 2048.. = W_v^T)
// cols <  2048 : kqb[row][col] = bf16((acc+b_kq[col]) * (col>=1024 ? 0.125 : 1))
// cols >= 2048 : vtb[col-2048][row] = bf16(acc + b_v[col-2048])   (transposed)

__global__ __launch_bounds__(256) void gemm_kqv(
    const unsigned short* __restrict__ A, const unsigned short* __restrict__ Bt,
    const float* __restrict__ b_kq, const float* __restrict__ b_v,
    unsigned short* __restrict__ kqb, unsigned short* __restrict__ vtb)
{
  const int tid  = threadIdx.x;
  const int lane = tid & 63;
  const int w    = tid >> 6;
  const int wm   = (w >> 1) * 64;
  const int wn   = (w & 1) * 64;
  const int n0   = blockIdx.x * 128;
  const int m0   = blockIdx.y * 128;
  const int quad = lane >> 4;
  const int l15  = lane & 15;
  const int K    = 1024;

  __shared__ __align__(16) unsigned short As[128 * 64];
  __shared__ __align__(16) unsigned short Bs[128 * 64];

  const int srow = lane >> 3;
  const int sc   = (lane & 7) ^ srow;

  const unsigned short* gA = A  + (size_t)(m0 + w * 32 + srow) * K + sc * 8;
  const unsigned short* gB = Bt + (size_t)(n0 + w * 32 + srow) * K + sc * 8;

  f32x4 acc[4][4] = {};

  for (int k0 = 0; k0 < K; k0 += 64) {
    __syncthreads();
#pragma unroll
    for (int i = 0; i < 4; ++i) {
      load_lds16(gA + (size_t)i * 8 * K + k0, &As[(w * 32 + i * 8) * 64 + lane * 8]);
      load_lds16(gB + (size_t)i * 8 * K + k0, &Bs[(w * 32 + i * 8) * 64 + lane * 8]);
    }
    __syncthreads();
#pragma unroll
    for (int kf = 0; kf < 2; ++kf) {
      frag_ab af[4], bf[4];
#pragma unroll
      for (int t = 0; t < 4; ++t) {
        const int ra = wm + t * 16 + l15;
        const int pa = (kf * 4 + quad) ^ (ra & 7);
        af[t] = *(const frag_ab*)&As[ra * 64 + pa * 8];
        const int rb = wn + t * 16 + l15;
        const int pb = (kf * 4 + quad) ^ (rb & 7);
        bf[t] = *(const frag_ab*)&Bs[rb * 64 + pb * 8];
      }
#pragma unroll
      for (int i = 0; i < 4; ++i)
#pragma unroll
        for (int j = 0; j < 4; ++j)
          acc[i][j] = __builtin_amdgcn_mfma_f32_16x16x32_bf16(
              af[i], bf[j], acc[i][j], 0, 0, 0);
    }
  }

  if (n0 >= 2048) {
    // v half -> transposed store
#pragma unroll
    for (int i = 0; i < 4; ++i)
#pragma unroll
      for (int j = 0; j < 4; ++j) {
        const int row0 = m0 + wm + i * 16 + quad * 4;
        const int col  = n0 - 2048 + wn + j * 16 + l15;
        const float bv = b_v[col];
        ushort4 pk;
        pk.x = f2bf(acc[i][j][0] + bv);
        pk.y = f2bf(acc[i][j][1] + bv);
        pk.z = f2bf(acc[i][j][2] + bv);
        pk.w = f2bf(acc[i][j][3] + bv);
        *(ushort4*)&vtb[(size_t)col * BL + row0] = pk;
      }
  } else {
    const float sc2 = (n0 + wn >= 1024) ? 0.125f : 1.0f;  // uniform per wave tile
#pragma unroll
    for (int i = 0; i < 4; ++i)
#pragma unroll
      for (int j = 0; j < 4; ++j) {
        const int row0 = m0 + wm + i * 16 + quad * 4;
        const int col  = n0 + wn + j * 16 + l15;
        const float bv = b_kq[col];
#pragma unroll
        for (int r = 0; r < 4; ++r)
          kqb[(size_t)(row0 + r) * 2048 + col] = f2bf((acc[i][j][r] + bv) * sc2);
      }
  }
}

// ---------------- output GEMM, split-K=2, atomic accumulate ----------------

__global__ __launch_bounds__(256) void gemm_out(
    const unsigned short* __restrict__ A, const unsigned short* __restrict__ Bt,
    const float* __restrict__ bias, float* __restrict__ C)
{
  const int tid  = threadIdx.x;
  const int lane = tid & 63;
  const int w    = tid >> 6;
  const int wm   = (w >> 1) * 64;
  const int wn   = (w & 1) * 64;
  const int n0   = blockIdx.x * 128;
  const int m0   = blockIdx.y * 128;
  const int ks   = blockIdx.z;
  const int quad = lane >> 4;
  const int l15  = lane & 15;
  const int K    = 1024;

  __shared__ __align__(16) unsigned short As[128 * 64];
  __shared__ __align__(16) unsigned short Bs[128 * 64];

  const int srow = lane >> 3;
  const int sc   = (lane & 7) ^ srow;

  const unsigned short* gA = A  + (size_t)(m0 + w * 32 + srow) * K + sc * 8;
  const unsigned short* gB = Bt + (size_t)(n0 + w * 32 + srow) * K + sc * 8;

  f32x4 acc[4][4] = {};

  for (int k0 = ks * 512; k0 < ks * 512 + 512; k0 += 64) {
    __syncthreads();
#pragma unroll
    for (int i = 0; i < 4; ++i) {
      load_lds16(gA + (size_t)i * 8 * K + k0, &As[(w * 32 + i * 8) * 64 + lane * 8]);
      load_lds16(gB + (size_t)i * 8 * K + k0, &Bs[(w * 32 + i * 8) * 64 + lane * 8]);
    }
    __syncthreads();
#pragma unroll
    for (int kf = 0; kf < 2; ++kf) {
      frag_ab af[4], bf[4];
#pragma unroll
      for (int t = 0; t < 4; ++t) {
        const int ra = wm + t * 16 + l15;
        const int pa = (kf * 4 + quad) ^ (ra & 7);
        af[t] = *(const frag_ab*)&As[ra * 64 + pa * 8];
        const int rb = wn + t * 16 + l15;
        const int pb = (kf * 4 + quad) ^ (rb & 7);
        bf[t] = *(const frag_ab*)&Bs[rb * 64 + pb * 8];
      }
#pragma unroll
      for (int i = 0; i < 4; ++i)
#pragma unroll
        for (int j = 0; j < 4; ++j)
          acc[i][j] = __builtin_amdgcn_mfma_f32_16x16x32_bf16(
              af[i], bf[j], acc[i][j], 0, 0, 0);
    }
  }

#pragma unroll
  for (int i = 0; i < 4; ++i)
#pragma unroll
    for (int j = 0; j < 4; ++j) {
      const int row0 = m0 + wm + i * 16 + quad * 4;
      const int col  = n0 + wn + j * 16 + l15;
      const float bv = (ks == 0) ? bias[col] : 0.0f;
#pragma unroll
      for (int r = 0; r < 4; ++r)
        atomicAdd(&C[(size_t)(row0 + r) * DM + col], acc[i][j][r] + bv);
    }
}

// ---------------- flash attention: S^T formulation ----------------
// kq: bf16 [BL][2048] (k cols 0..1023, q cols 1024..2047 pre-scaled 0.125)
// vt: bf16 [1024][BL]; att: bf16 [BL][1024]
// Block: 64 q-rows (4 waves x 16), K-tile 128. Per lane: one q-row (l15).

__global__ __launch_bounds__(256) void attn_mfma(
    const unsigned short* __restrict__ kq, const unsigned short* __restrict__ vt,
    unsigned short* __restrict__ att)
{
  const int tid  = threadIdx.x;
  const int lane = tid & 63;
  const int w    = tid >> 6;
  const int bx   = blockIdx.x;
  const int qt   = 31 - (bx >> 5);   // heavy q-tiles first
  const int bh   = bx & 31;
  const int b    = bh >> 4;
  const int h    = bh & 15;
  const int q0   = qt * 64;
  const int quad = lane >> 4;
  const int l15  = lane & 15;

  __shared__ __align__(16) unsigned short Ks[128 * 64];   // keys x d   (16 KB)
  __shared__ __align__(16) unsigned short Vs[64 * 128];   // d x keys   (16 KB)
  __shared__ __align__(16) unsigned short Ps[4 * 16 * 128]; // per-wave P (16 KB)

  // ---- stage Q (64 x 64) into Ks region, read frags to regs, then reuse ----
#pragma unroll
  for (int i = 0; i < 2; ++i) {
    const int L = i * 256 + tid;         // 0..511
    const int row = L >> 3, c = L & 7;
    const unsigned short* g = kq + (size_t)(b * LSEQ + q0 + row) * 2048
                                 + DM + h * 64 + ((c ^ (row & 7)) * 8);
    load_lds16(g, &Ks[(size_t)L * 8]);
  }
  __syncthreads();
  frag_ab qa[2];
#pragma unroll
  for (int kf = 0; kf < 2; ++kf) {
    const int row = w * 16 + l15;
    const int c = (kf * 4 + quad) ^ (row & 7);
    qa[kf] = *(const frag_ab*)&Ks[row * 64 + c * 8];
  }

  f32x4 oacc[4] = {};
  float mrow = -3e38f, lrow = 0.f;
  const int nk = (qt + 2) >> 1;
  unsigned short* Pw = &Ps[w * 2048];

  for (int kt = 0; kt < nk; ++kt) {
    const int k0 = kt * 128;
    __syncthreads();   // everyone done with Ks/Vs (and qa regs read)
#pragma unroll
    for (int i = 0; i < 4; ++i) {
      const int L = i * 256 + tid;       // 0..1023
      { // K: 128 rows x 8 chunks
        const int row = L >> 3, c = L & 7;
        const unsigned short* g = kq + (size_t)(b * LSEQ + k0 + row) * 2048
                                     + h * 64 + ((c ^ (row & 7)) * 8);
        load_lds16(g, &Ks[(size_t)L * 8]);
      }
      { // V^T: 64 rows(d) x 16 chunks
        const int row = L >> 4, c = L & 15;
        const unsigned short* g = vt + (size_t)(h * 64 + row) * BL
                                     + b * LSEQ + k0 + ((c ^ (row & 7)) * 8);
        load_lds16(g, &Vs[(size_t)L * 8]);
      }
    }
    __syncthreads();

    // S^T = K @ Q^T : st[mt][r] = score(key = k0+mt*16+quad*4+r, qrow = l15)
    f32x4 st[8];
#pragma unroll
    for (int mt = 0; mt < 8; ++mt) {
      f32x4 s = {};
#pragma unroll
      for (int kf = 0; kf < 2; ++kf) {
        const int row = mt * 16 + l15;
        const int c = (kf * 4 + quad) ^ (row & 7);
        const frag_ab kfrag = *(const frag_ab*)&Ks[row * 64 + c * 8];
        s = __builtin_amdgcn_mfma_f32_16x16x32_bf16(kfrag, qa[kf], s, 0, 0, 0);
      }
      st[mt] = s;
    }

    if (kt == nk - 1) {   // causal mask, last tile only
      const int qg = q0 + w * 16 + l15;
#pragma unroll
      for (int mt = 0; mt < 8; ++mt)
#pragma unroll
        for (int r = 0; r < 4; ++r)
          if (k0 + mt * 16 + quad * 4 + r > qg) st[mt][r] = -3e38f;
    }

    // per-lane online softmax (one q-row per lane; reduce across 4 quads)
    float mx = -3e38f;
#pragma unroll
    for (int mt = 0; mt < 8; ++mt)
#pragma unroll
      for (int r = 0; r < 4; ++r) mx = fmaxf(mx, st[mt][r]);
    mx = fmaxf(mx, __shfl_xor(mx, 16));
    mx = fmaxf(mx, __shfl_xor(mx, 32));
    const float mnew  = fmaxf(mrow, mx);
    const float alpha = __expf(mrow - mnew);
    float rsum = 0.f;
#pragma unroll
    for (int mt = 0; mt < 8; ++mt)
#pragma unroll
      for (int r = 0; r < 4; ++r) {
        const float e = __expf(st[mt][r] - mnew);
        st[mt][r] = e;
        rsum += e;
      }
    rsum += __shfl_xor(rsum, 16);
    rsum += __shfl_xor(rsum, 32);
    lrow = lrow * alpha + rsum;
    mrow = mnew;
#pragma unroll
    for (int dt = 0; dt < 4; ++dt) oacc[dt] *= alpha;

    // pack P^T back as P[qrow][key] (8B stores, 16B-granular swizzle)
#pragma unroll
    for (int mt = 0; mt < 8; ++mt) {
      ushort4 pk;
      pk.x = f2bf(st[mt][0]); pk.y = f2bf(st[mt][1]);
      pk.z = f2bf(st[mt][2]); pk.w = f2bf(st[mt][3]);
      const int c8 = mt * 4 + quad;
      *(ushort4*)((char*)Pw + l15 * 256 + ((c8 ^ ((l15 & 7) << 1)) << 3)) = pk;
    }

    // O^T += V^T @ P^T  (A = Vs rows d, B = Ps rows qrow)
#pragma unroll
    for (int kf = 0; kf < 4; ++kf) {
      const frag_ab pfrag = *(const frag_ab*)(
          (const char*)Pw + l15 * 256 + ((((kf << 2) + quad) ^ (l15 & 7)) << 4));
#pragma unroll
      for (int dt = 0; dt < 4; ++dt) {
        const int row = dt * 16 + l15;
        const int c = ((kf << 2) + quad) ^ (row & 7);
        const frag_ab vfrag = *(const frag_ab*)&Vs[row * 128 + c * 8];
        oacc[dt] = __builtin_amdgcn_mfma_f32_16x16x32_bf16(vfrag, pfrag, oacc[dt], 0, 0, 0);
      }
    }
  }

  // epilogue: O^T[d][qrow] / l -> att[qrow][d]
  const float inv = 1.0f / lrow;
  const int row = b * LSEQ + q0 + w * 16 + l15;
#pragma unroll
  for (int dt = 0; dt < 4; ++dt) {
    ushort4 pk;
    pk.x = f2bf(oacc[dt][0] * inv);
    pk.y = f2bf(oacc[dt][1] * inv);
    pk.z = f2bf(oacc[dt][2] * inv);
    pk.w = f2bf(oacc[dt][3] * inv);
    const int col = h * 64 + dt * 16 + quad * 4;
    *(ushort4*)&att[(size_t)row * DM + col] = pk;
  }
}

// ---------------- launcher ----------------

extern "C" void kernel_launch(void* const* d_in, const int* in_sizes, int n_in,
                              void* d_out, int out_size, void* d_ws, size_t ws_size,
                              hipStream_t stream)
{
  const float* x    = (const float*)d_in[0];
  const float* W_kq = (const float*)d_in[1];
  const float* b_kq = (const float*)d_in[2];
  const float* W_v  = (const float*)d_in[3];
  const float* b_v  = (const float*)d_in[4];
  const float* W_o  = (const float*)d_in[5];
  const float* b_o  = (const float*)d_in[6];

  unsigned short* ws   = (unsigned short*)d_ws;
  unsigned short* xb   = ws;                    // 4096*1024
  unsigned short* wcat = xb   + 4194304;        // 3072*1024 ([W_kq|W_v]^T)
  unsigned short* wot  = wcat + 3145728;        // 1024*1024
  unsigned short* kqb  = wot  + 1048576;        // 4096*2048
  unsigned short* vtb  = kqb  + 8388608;        // 1024*4096
  unsigned short* attb = vtb  + 4194304;        // 4096*1024

  hipMemsetAsync(d_out, 0, (size_t)BL * DM * sizeof(float), stream);

  cast_bf16_kernel<<<4096, 256, 0, stream>>>(x, xb, 1048576);
  transpose_cast_kernel<<<dim3(64, 32), 256, 0, stream>>>(W_kq, wcat, 1024, 2048);
  transpose_cast_kernel<<<dim3(32, 32), 256, 0, stream>>>(W_v, wcat + 2097152, 1024, 1024);
  transpose_cast_kernel<<<dim3(32, 32), 256, 0, stream>>>(W_o, wot, 1024, 1024);

  // fused kq + v GEMM (24 x 32 = 768 blocks)
  gemm_kqv<<<dim3(24, 32), 256, 0, stream>>>(xb, wcat, b_kq, b_v, kqb, vtb);
  // attention (1024 blocks)
  attn_mfma<<<1024, 256, 0, stream>>>(kqb, vtb, attb);
  // out GEMM, split-K=2 (8 x 32 x 2 = 512 blocks)
  gemm_out<<<dim3(8, 32, 2), 256, 0, stream>>>(attb, wot, b_o, (float*)d_out);
}

// Round 5
// 197.281 us; speedup vs baseline: 1.3000x; 1.3000x over previous
//
#include <hip/hip_runtime.h>
#include <cstdint>

// CausalSelfAttention B=2 L=2048 D=1024 H=16 dh=64, fp32 in/out.
// Round 5 (R4 + compile fix):
//   prep : x->bf16 ; [W_kq|W_v]->wcat bf16 ; W_o->wot fp16
//   g1   : fused kqv GEMM -> kqb bf16 (q pre-scaled 0.125) + vtb fp16 (V^T)
//   attn : flash MFMA, S^T via 16x16x32_bf16, PV via 16x16x16_f16 with
//          REGISTER-LOCAL P (C-layout of S^T == A-layout of K=16 mfma).
//          LDS 32KB (K 16K + V^T 16K), no P buffer. -> attb fp16
//   g2   : out = attb @ wot^T + b_o  (fp16 mfma, fp32 store, 256 blocks)

#define LSEQ 2048
#define DM   1024
#define BL   4096   // B * LSEQ

using frag_ab = __attribute__((ext_vector_type(8))) short;     // 8 bf16
using half8   = __attribute__((ext_vector_type(8))) _Float16;  // 8 fp16
using half4   = __attribute__((ext_vector_type(4))) _Float16;
using f32x4   = __attribute__((ext_vector_type(4))) float;

__device__ __forceinline__ unsigned short f2bf(float f) {
  unsigned int u = __float_as_uint(f);
  u += 0x7fffu + ((u >> 16) & 1u);   // RNE (finite inputs only)
  return (unsigned short)(u >> 16);
}

__device__ __forceinline__ void load_lds16(const void* g, void* l) {
  __builtin_amdgcn_global_load_lds(
      (const __attribute__((address_space(1))) unsigned int*)g,
      (__attribute__((address_space(3))) unsigned int*)l, 16, 0, 0);
}

// ---------------- prep kernels ----------------

__global__ __launch_bounds__(256) void cast_bf16_kernel(
    const float* __restrict__ in, unsigned short* __restrict__ out, int n4)
{
  int i = (blockIdx.x * 256 + threadIdx.x);
  if (i < n4) {
    const float4 v = *(const float4*)&in[i * 4];
    ushort4 o;
    o.x = f2bf(v.x); o.y = f2bf(v.y); o.z = f2bf(v.z); o.w = f2bf(v.w);
    *(ushort4*)&out[i * 4] = o;
  }
}

// W (K x N fp32) -> Wt (N x K bf16)
__global__ __launch_bounds__(256) void transpose_cast_kernel(
    const float* __restrict__ W, unsigned short* __restrict__ Wt, int K, int N)
{
  __shared__ float tile[32][33];
  const int r  = threadIdx.x >> 3;
  const int c4 = (threadIdx.x & 7) * 4;
  const int kb = blockIdx.y * 32;
  const int nb = blockIdx.x * 32;

  const float4 v = *(const float4*)&W[(size_t)(kb + r) * N + nb + c4];
  tile[r][c4 + 0] = v.x; tile[r][c4 + 1] = v.y;
  tile[r][c4 + 2] = v.z; tile[r][c4 + 3] = v.w;
  __syncthreads();
  ushort4 o;
  o.x = f2bf(tile[c4 + 0][r]);
  o.y = f2bf(tile[c4 + 1][r]);
  o.z = f2bf(tile[c4 + 2][r]);
  o.w = f2bf(tile[c4 + 3][r]);
  *(ushort4*)&Wt[(size_t)(nb + r) * K + kb + c4] = o;
}

// W (K x N fp32) -> Wt (N x K fp16)
__global__ __launch_bounds__(256) void transpose_cast_f16_kernel(
    const float* __restrict__ W, _Float16* __restrict__ Wt, int K, int N)
{
  __shared__ float tile[32][33];
  const int r  = threadIdx.x >> 3;
  const int c4 = (threadIdx.x & 7) * 4;
  const int kb = blockIdx.y * 32;
  const int nb = blockIdx.x * 32;

  const float4 v = *(const float4*)&W[(size_t)(kb + r) * N + nb + c4];
  tile[r][c4 + 0] = v.x; tile[r][c4 + 1] = v.y;
  tile[r][c4 + 2] = v.z; tile[r][c4 + 3] = v.w;
  __syncthreads();
  half4 o;
  o[0] = (_Float16)tile[c4 + 0][r];
  o[1] = (_Float16)tile[c4 + 1][r];
  o[2] = (_Float16)tile[c4 + 2][r];
  o[3] = (_Float16)tile[c4 + 3][r];
  *(half4*)&Wt[(size_t)(nb + r) * K + kb + c4] = o;
}

// ---------------- fused kqv GEMM ----------------
// A = xb [4096x1024] bf16, Bt = wcat [3072x1024] bf16
// cols <  2048 : kqb[row][col] = bf16((acc+b_kq[col]) * (col>=1024 ? 0.125 : 1))
// cols >= 2048 : vtb[col-2048][row] = fp16(acc + b_v[col-2048])   (V^T)

__global__ __launch_bounds__(256) void gemm_kqv(
    const unsigned short* __restrict__ A, const unsigned short* __restrict__ Bt,
    const float* __restrict__ b_kq, const float* __restrict__ b_v,
    unsigned short* __restrict__ kqb, _Float16* __restrict__ vtb)
{
  const int tid  = threadIdx.x;
  const int lane = tid & 63;
  const int w    = tid >> 6;
  const int wm   = (w >> 1) * 64;
  const int wn   = (w & 1) * 64;
  const int n0   = blockIdx.x * 128;
  const int m0   = blockIdx.y * 128;
  const int quad = lane >> 4;
  const int l15  = lane & 15;
  const int K    = 1024;

  __shared__ __align__(16) unsigned short As[128 * 64];
  __shared__ __align__(16) unsigned short Bs[128 * 64];

  const int srow = lane >> 3;
  const int sc   = (lane & 7) ^ srow;

  const unsigned short* gA = A  + (size_t)(m0 + w * 32 + srow) * K + sc * 8;
  const unsigned short* gB = Bt + (size_t)(n0 + w * 32 + srow) * K + sc * 8;

  f32x4 acc[4][4] = {};

  for (int k0 = 0; k0 < K; k0 += 64) {
    __syncthreads();
#pragma unroll
    for (int i = 0; i < 4; ++i) {
      load_lds16(gA + (size_t)i * 8 * K + k0, &As[(w * 32 + i * 8) * 64 + lane * 8]);
      load_lds16(gB + (size_t)i * 8 * K + k0, &Bs[(w * 32 + i * 8) * 64 + lane * 8]);
    }
    __syncthreads();
#pragma unroll
    for (int kf = 0; kf < 2; ++kf) {
      frag_ab af[4], bf[4];
#pragma unroll
      for (int t = 0; t < 4; ++t) {
        const int ra = wm + t * 16 + l15;
        const int pa = (kf * 4 + quad) ^ (ra & 7);
        af[t] = *(const frag_ab*)&As[ra * 64 + pa * 8];
        const int rb = wn + t * 16 + l15;
        const int pb = (kf * 4 + quad) ^ (rb & 7);
        bf[t] = *(const frag_ab*)&Bs[rb * 64 + pb * 8];
      }
#pragma unroll
      for (int i = 0; i < 4; ++i)
#pragma unroll
        for (int j = 0; j < 4; ++j)
          acc[i][j] = __builtin_amdgcn_mfma_f32_16x16x32_bf16(
              af[i], bf[j], acc[i][j], 0, 0, 0);
    }
  }

  if (n0 >= 2048) {
#pragma unroll
    for (int i = 0; i < 4; ++i)
#pragma unroll
      for (int j = 0; j < 4; ++j) {
        const int row0 = m0 + wm + i * 16 + quad * 4;
        const int col  = n0 - 2048 + wn + j * 16 + l15;
        const float bv = b_v[col];
        half4 pk;
        pk[0] = (_Float16)(acc[i][j][0] + bv);
        pk[1] = (_Float16)(acc[i][j][1] + bv);
        pk[2] = (_Float16)(acc[i][j][2] + bv);
        pk[3] = (_Float16)(acc[i][j][3] + bv);
        *(half4*)&vtb[(size_t)col * BL + row0] = pk;
      }
  } else {
    const float sc2 = (n0 + wn >= 1024) ? 0.125f : 1.0f;
#pragma unroll
    for (int i = 0; i < 4; ++i)
#pragma unroll
      for (int j = 0; j < 4; ++j) {
        const int row0 = m0 + wm + i * 16 + quad * 4;
        const int col  = n0 + wn + j * 16 + l15;
        const float bv = b_kq[col];
#pragma unroll
        for (int r = 0; r < 4; ++r)
          kqb[(size_t)(row0 + r) * 2048 + col] = f2bf((acc[i][j][r] + bv) * sc2);
      }
  }
}

// ---------------- output GEMM (fp16 operands, fp32 out) ----------------

__global__ __launch_bounds__(256) void gemm_out(
    const _Float16* __restrict__ A, const _Float16* __restrict__ Bt,
    const float* __restrict__ bias, float* __restrict__ C)
{
  const int tid  = threadIdx.x;
  const int lane = tid & 63;
  const int w    = tid >> 6;
  const int wm   = (w >> 1) * 64;
  const int wn   = (w & 1) * 64;
  const int n0   = blockIdx.x * 128;
  const int m0   = blockIdx.y * 128;
  const int quad = lane >> 4;
  const int l15  = lane & 15;
  const int K    = 1024;

  __shared__ __align__(16) _Float16 As[128 * 64];
  __shared__ __align__(16) _Float16 Bs[128 * 64];

  const int srow = lane >> 3;
  const int sc   = (lane & 7) ^ srow;

  const _Float16* gA = A  + (size_t)(m0 + w * 32 + srow) * K + sc * 8;
  const _Float16* gB = Bt + (size_t)(n0 + w * 32 + srow) * K + sc * 8;

  f32x4 acc[4][4] = {};

  for (int k0 = 0; k0 < K; k0 += 64) {
    __syncthreads();
#pragma unroll
    for (int i = 0; i < 4; ++i) {
      load_lds16(gA + (size_t)i * 8 * K + k0, &As[(w * 32 + i * 8) * 64 + lane * 8]);
      load_lds16(gB + (size_t)i * 8 * K + k0, &Bs[(w * 32 + i * 8) * 64 + lane * 8]);
    }
    __syncthreads();
#pragma unroll
    for (int kf = 0; kf < 2; ++kf) {
      half8 af[4], bf[4];
#pragma unroll
      for (int t = 0; t < 4; ++t) {
        const int ra = wm + t * 16 + l15;
        const int pa = (kf * 4 + quad) ^ (ra & 7);
        af[t] = *(const half8*)&As[ra * 64 + pa * 8];
        const int rb = wn + t * 16 + l15;
        const int pb = (kf * 4 + quad) ^ (rb & 7);
        bf[t] = *(const half8*)&Bs[rb * 64 + pb * 8];
      }
#pragma unroll
      for (int i = 0; i < 4; ++i)
#pragma unroll
        for (int j = 0; j < 4; ++j)
          acc[i][j] = __builtin_amdgcn_mfma_f32_16x16x32_f16(
              af[i], bf[j], acc[i][j], 0, 0, 0);
    }
  }

#pragma unroll
  for (int i = 0; i < 4; ++i)
#pragma unroll
    for (int j = 0; j < 4; ++j) {
      const int row0 = m0 + wm + i * 16 + quad * 4;
      const int col  = n0 + wn + j * 16 + l15;
      const float bv = bias[col];
#pragma unroll
      for (int r = 0; r < 4; ++r)
        C[(size_t)(row0 + r) * DM + col] = acc[i][j][r] + bv;
    }
}

// ---------------- flash attention ----------------
// kq: bf16 [BL][2048] (k cols 0..1023, q cols 1024..2047 pre-scaled 0.125)
// vt: fp16 [1024][BL] (V^T); att: fp16 [BL][1024]
// Block: 64 q-rows (4 waves x 16), K-tile 128. Lane owns q-row l15 for softmax.
// S^T via mfma_16x16x32_bf16; PV via mfma_16x16x16_f16 with register-local P
// (S^T C-layout == A-layout of the K=16 mfma). O in C-layout: d=l15, qrow=quad*4+r.

__global__ __launch_bounds__(256) void attn_mfma(
    const unsigned short* __restrict__ kq, const _Float16* __restrict__ vt,
    _Float16* __restrict__ att)
{
  const int tid  = threadIdx.x;
  const int lane = tid & 63;
  const int w    = tid >> 6;
  const int bx   = blockIdx.x;
  const int qt   = 31 - (bx >> 5);   // heavy q-tiles first
  const int bh   = bx & 31;
  const int b    = bh >> 4;
  const int h    = bh & 15;
  const int q0   = qt * 64;
  const int quad = lane >> 4;
  const int l15  = lane & 15;

  __shared__ __align__(16) unsigned short Ks[128 * 64];  // keys x d, bf16 (16KB)
  __shared__ __align__(16) _Float16      Vs[64 * 128];   // d x keys, fp16 (16KB)

  // ---- stage Q (64x64) into Ks region, read frags, then reuse Ks for K ----
#pragma unroll
  for (int i = 0; i < 2; ++i) {
    const int L = i * 256 + tid;        // 0..511
    const int row = L >> 3, c = L & 7;
    const unsigned short* g = kq + (size_t)(b * LSEQ + q0 + row) * 2048
                                 + DM + h * 64 + ((c ^ (row & 7)) * 8);
    load_lds16(g, &Ks[(size_t)L * 8]);
  }
  __syncthreads();
  frag_ab qa[2];
#pragma unroll
  for (int kf = 0; kf < 2; ++kf) {
    const int row = w * 16 + l15;
    const int c = (kf * 4 + quad) ^ (row & 7);
    qa[kf] = *(const frag_ab*)&Ks[row * 64 + c * 8];
  }

  f32x4 oacc[4] = {};
  float mrow = -3e38f, lrow = 0.f;
  const int nk = (qt + 2) >> 1;

  for (int kt = 0; kt < nk; ++kt) {
    const int k0 = kt * 128;
    __syncthreads();   // everyone done reading Ks/Vs (and qa regs loaded)
#pragma unroll
    for (int i = 0; i < 4; ++i) {
      const int L = i * 256 + tid;      // 0..1023
      { // K: 128 rows x 8 chunks of 16B
        const int row = L >> 3, c = L & 7;
        const unsigned short* g = kq + (size_t)(b * LSEQ + k0 + row) * 2048
                                     + h * 64 + ((c ^ (row & 7)) * 8);
        load_lds16(g, &Ks[(size_t)L * 8]);
      }
      { // V^T: 64 rows (d) x 16 chunks of 16B
        const int row = L >> 4, c16 = L & 15;
        const _Float16* g = vt + (size_t)(h * 64 + row) * BL
                               + b * LSEQ + k0 + ((c16 ^ (row & 15)) * 8);
        load_lds16(g, &Vs[(size_t)L * 8]);
      }
    }
    __syncthreads();

    // S^T = K @ Q^T : st[mt][r] = score(key = k0+mt*16+quad*4+r, qrow = l15)
    f32x4 st[8];
#pragma unroll
    for (int mt = 0; mt < 8; ++mt) {
      f32x4 s = {};
#pragma unroll
      for (int kf = 0; kf < 2; ++kf) {
        const int row = mt * 16 + l15;
        const int c = (kf * 4 + quad) ^ (row & 7);
        const frag_ab kfrag = *(const frag_ab*)&Ks[row * 64 + c * 8];
        s = __builtin_amdgcn_mfma_f32_16x16x32_bf16(kfrag, qa[kf], s, 0, 0, 0);
      }
      st[mt] = s;
    }

    if (kt == nk - 1) {   // causal mask (last tile only)
      const int qg = q0 + w * 16 + l15;
#pragma unroll
      for (int mt = 0; mt < 8; ++mt)
#pragma unroll
        for (int r = 0; r < 4; ++r)
          if (k0 + mt * 16 + quad * 4 + r > qg) st[mt][r] = -3e38f;
    }

    // per-lane online softmax for q-row l15 (reduce across the 4 quads)
    float mx = -3e38f;
#pragma unroll
    for (int mt = 0; mt < 8; ++mt)
#pragma unroll
      for (int r = 0; r < 4; ++r) mx = fmaxf(mx, st[mt][r]);
    mx = fmaxf(mx, __shfl_xor(mx, 16));
    mx = fmaxf(mx, __shfl_xor(mx, 32));
    const float mnew  = fmaxf(mrow, mx);
    const float alpha = __expf(mrow - mnew);
    float rsum = 0.f;
#pragma unroll
    for (int mt = 0; mt < 8; ++mt)
#pragma unroll
      for (int r = 0; r < 4; ++r) {
        const float e = __expf(st[mt][r] - mnew);
        st[mt][r] = e;
        rsum += e;
      }
    rsum += __shfl_xor(rsum, 16);
    rsum += __shfl_xor(rsum, 32);
    lrow = lrow * alpha + rsum;
    mrow = mnew;

    // rescale O: alpha for q-row quad*4+r lives in lane (quad*4+r) of this row group
    float aq[4];
#pragma unroll
    for (int r = 0; r < 4; ++r) aq[r] = __shfl(alpha, quad * 4 + r);
#pragma unroll
    for (int dt = 0; dt < 4; ++dt)
#pragma unroll
      for (int r = 0; r < 4; ++r) oacc[dt][r] *= aq[r];

    // O += P @ V : P is register-local (st in C-layout == A-layout of K=16 mfma)
#pragma unroll
    for (int c8 = 0; c8 < 8; ++c8) {
      half4 pf;
      pf[0] = (_Float16)st[c8][0];
      pf[1] = (_Float16)st[c8][1];
      pf[2] = (_Float16)st[c8][2];
      pf[3] = (_Float16)st[c8][3];
#pragma unroll
      for (int dt = 0; dt < 4; ++dt) {
        const int g16 = 2 * c8 + (quad >> 1);
        const half4 vf = *(const half4*)&Vs[(dt * 16 + l15) * 128
                                            + ((g16 ^ l15) << 3) + ((quad & 1) << 2)];
        oacc[dt] = __builtin_amdgcn_mfma_f32_16x16x16f16(pf, vf, oacc[dt], 0, 0, 0);
      }
    }
  }

  // epilogue: lane holds O[qrow=quad*4+r][d=dt*16+l15]; divide by l, store fp16
  float lq[4];
#pragma unroll
  for (int r = 0; r < 4; ++r) lq[r] = 1.0f / __shfl(lrow, quad * 4 + r);
#pragma unroll
  for (int dt = 0; dt < 4; ++dt)
#pragma unroll
    for (int r = 0; r < 4; ++r) {
      const int row = b * LSEQ + q0 + w * 16 + quad * 4 + r;
      const int col = h * 64 + dt * 16 + l15;
      att[(size_t)row * DM + col] = (_Float16)(oacc[dt][r] * lq[r]);
    }
}

// ---------------- launcher ----------------

extern "C" void kernel_launch(void* const* d_in, const int* in_sizes, int n_in,
                              void* d_out, int out_size, void* d_ws, size_t ws_size,
                              hipStream_t stream)
{
  const float* x    = (const float*)d_in[0];
  const float* W_kq = (const float*)d_in[1];
  const float* b_kq = (const float*)d_in[2];
  const float* W_v  = (const float*)d_in[3];
  const float* b_v  = (const float*)d_in[4];
  const float* W_o  = (const float*)d_in[5];
  const float* b_o  = (const float*)d_in[6];

  unsigned short* ws   = (unsigned short*)d_ws;
  unsigned short* xb   = ws;                    // 4096*1024 bf16
  unsigned short* wcat = xb   + 4194304;        // 3072*1024 bf16
  _Float16*       wot  = (_Float16*)(wcat + 3145728);   // 1024*1024 fp16
  unsigned short* kqb  = (unsigned short*)(wot + 1048576); // 4096*2048 bf16
  _Float16*       vtb  = (_Float16*)(kqb + 8388608);    // 1024*4096 fp16
  _Float16*       attb = vtb + 4194304;         // 4096*1024 fp16

  cast_bf16_kernel<<<4096, 256, 0, stream>>>(x, xb, 1048576);
  transpose_cast_kernel<<<dim3(64, 32), 256, 0, stream>>>(W_kq, wcat, 1024, 2048);
  transpose_cast_kernel<<<dim3(32, 32), 256, 0, stream>>>(W_v, wcat + 2097152, 1024, 1024);
  transpose_cast_f16_kernel<<<dim3(32, 32), 256, 0, stream>>>(W_o, wot, 1024, 1024);

  // fused kq + v GEMM (24 x 32 = 768 blocks)
  gemm_kqv<<<dim3(24, 32), 256, 0, stream>>>(xb, wcat, b_kq, b_v, kqb, vtb);
  // attention (1024 blocks)
  attn_mfma<<<1024, 256, 0, stream>>>(kqb, vtb, attb);
  // out = att @ Wo^T + b_o (8 x 32 = 256 blocks)
  gemm_out<<<dim3(8, 32), 256, 0, stream>>>(attb, wot, b_o, (float*)d_out);
}